// Round 10
// baseline (604.177 us; speedup 1.0000x reference)
//
#include <hip/hip_runtime.h>
#include <hip/hip_bf16.h>
#include <stdint.h>

// ResRnn via first-order expansion in eps (method err ~1e-3 << 2.62):
//   tables: pi^t / pi^-t via composition doubling
//   stage1: permuted prefix sum -> U (bf16) + ULAST (fp32)  [8-deep reg-gather]
//   k_mlp : FUSED F = relu(U@W1^T+b1)@W2^T + b2  [64KB LDS -> 2 blocks/CU]
//   stage3: e-reduction as register gather with inverse table [8-deep]
//   final : exact fp32 last step (+ fused s3b column-sum/gather).

#define T_STEPS 2048
#define BATCH 64
#define IN_W 256
#define SW 512
#define EPS 1e-5f
#define NCHUNK 64
#define CLEN 32
#define QSTEP 32
#define NQ 65

typedef __bf16 bf16x8 __attribute__((ext_vector_type(8)));
typedef float f32x4 __attribute__((ext_vector_type(4)));

__device__ __forceinline__ unsigned short bf16bits(float v) {
  __hip_bfloat16 h = __float2bfloat16(v);
  return *reinterpret_cast<unsigned short*>(&h);
}

__device__ __forceinline__ float bf16val(unsigned short u) {
  unsigned int x = ((unsigned int)u) << 16;
  return __uint_as_float(x);
}

__device__ __forceinline__ void gload_lds16(const void* g, const void* l) {
  __builtin_amdgcn_global_load_lds(
      (const __attribute__((address_space(1))) unsigned int*)(uintptr_t)g,
      (__attribute__((address_space(3))) unsigned int*)(uintptr_t)l, 16, 0, 0);
}

// ---------------- permutation power tables (doubling) ------------------------
__global__ __launch_bounds__(512) void k_tabA(const int* __restrict__ perm,
                                              int* __restrict__ FW, int* __restrict__ IDXI) {
  __shared__ int pl[SW], il[SW];
  int j = threadIdx.x;
  pl[j] = perm[j];
  __syncthreads();
  il[pl[j]] = j;
  __syncthreads();
  int f = j, iv = j;
  FW[j] = f; IDXI[j] = iv;
  for (int t = 1; t <= QSTEP; ++t) {
    f = pl[f]; iv = il[iv];
    FW[t * SW + j] = f; IDXI[t * SW + j] = iv;
  }
}

__global__ __launch_bounds__(512) void k_tabB(const int* __restrict__ FW, const int* __restrict__ IDXI,
                                              int* __restrict__ FWQ, int* __restrict__ IDXIQ) {
  __shared__ int f32r[SW], i32r[SW];
  int j = threadIdx.x;
  f32r[j] = FW[QSTEP * SW + j];
  i32r[j] = IDXI[QSTEP * SW + j];
  __syncthreads();
  int f = j, iv = j;
  FWQ[j] = f; IDXIQ[j] = iv;
  for (int q = 1; q < NQ; ++q) {
    f = f32r[f]; iv = i32r[iv];
    FWQ[q * SW + j] = f; IDXIQ[q * SW + j] = iv;
  }
}

__global__ __launch_bounds__(512) void k_tabC(const int* __restrict__ FWQ, const int* __restrict__ IDXIQ,
                                              int* __restrict__ FW, int* __restrict__ IDXI) {
  int t = blockIdx.x;
  if (t <= QSTEP) return;
  int j = threadIdx.x;
  int q = t >> 5, r = t & 31;
  int a = FW[r * SW + j];
  FW[(size_t)t * SW + j] = FWQ[q * SW + a];
  int b = IDXI[r * SW + j];
  IDXI[(size_t)t * SW + j] = IDXIQ[q * SW + b];
}

// ---------------- weights -> bf16 --------------------------------------------
__global__ __launch_bounds__(256) void k_wcast(const float* __restrict__ W1,
                                               const float* __restrict__ W2,
                                               __hip_bfloat16* __restrict__ W1b,
                                               __hip_bfloat16* __restrict__ W2b) {
  int i = blockIdx.x * 256 + threadIdx.x;
  if (i < SW * SW) W1b[i] = __float2bfloat16(W1[i]);
  else W2b[i - SW * SW] = __float2bfloat16(W2[i - SW * SW]);
}

// ---------------- stage 1a: chunk sums, 8-deep staged register gather --------
__global__ __launch_bounds__(512) void k_s1a(const float* __restrict__ x,
                                             const int* __restrict__ IDXI,
                                             float* __restrict__ P1) {
  __shared__ float xs[8][IN_W] __attribute__((aligned(16)));
  int c = blockIdx.x, b = blockIdx.y, tid = threadIdx.x;
  const int r = tid >> 6;
  const int colx = (tid & 63) * 4;
  float acc = 0.f;
  int t0 = c * CLEN;
  for (int tt = 0; tt < CLEN; tt += 8) {
    *reinterpret_cast<f32x4*>(&xs[r][colx]) =
        *reinterpret_cast<const f32x4*>(&x[((size_t)(t0 + tt + r) * BATCH + b) * IN_W + colx]);
    __syncthreads();
#pragma unroll
    for (int k = 0; k < 8; ++k) {
      int i0 = IDXI[(size_t)(t0 + tt + k) * SW + tid];
      if (i0 < IN_W) acc += xs[k][i0];
    }
    __syncthreads();
  }
  P1[((size_t)c * BATCH + b) * SW + tid] = acc;
}

__global__ __launch_bounds__(512) void k_s1b(const float* __restrict__ init,
                                             float* __restrict__ P1) {
  int b = blockIdx.x, i = threadIdx.x;
  float run = EPS * init[i];
  for (int c = 0; c < NCHUNK; ++c) {
    size_t o = ((size_t)c * BATCH + b) * SW + i;
    float t = P1[o]; P1[o] = run; run += t;
  }
}

// ---------------- stage 1c: prefix walk, 8-deep staging, coalesced U dump ----
__global__ __launch_bounds__(512) void k_s1c(const float* __restrict__ x,
                                             const int* __restrict__ IDXI,
                                             const float* __restrict__ P1,
                                             __hip_bfloat16* __restrict__ U,
                                             float* __restrict__ ULAST) {
  __shared__ float xs[8][IN_W] __attribute__((aligned(16)));
  __shared__ unsigned short us[8][SW] __attribute__((aligned(16)));
  __shared__ float ul[SW] __attribute__((aligned(16)));
  int c = blockIdx.x, b = blockIdx.y, tid = threadIdx.x;
  float v = P1[((size_t)c * BATCH + b) * SW + tid];
  int t0 = c * CLEN;
  const int r = tid >> 6;
  const int colx = (tid & 63) * 4;
  const int colu = (tid & 63) * 8;
  for (int tt = 0; tt < CLEN; tt += 8) {
    *reinterpret_cast<f32x4*>(&xs[r][colx]) =
        *reinterpret_cast<const f32x4*>(&x[((size_t)(t0 + tt + r) * BATCH + b) * IN_W + colx]);
    __syncthreads();
#pragma unroll
    for (int k = 0; k < 8; ++k) {
      int t = t0 + tt + k;
      int i0 = IDXI[(size_t)t * SW + tid];
      int i1 = IDXI[(size_t)(t + 1) * SW + tid];
      if (i0 < IN_W) v += xs[k][i0];
      us[k][i1] = bf16bits(v);
      if (t == T_STEPS - 1) ul[i1] = v;
    }
    __syncthreads();
    *reinterpret_cast<int4*>(&U[((size_t)(t0 + tt + r) * BATCH + b) * SW + colu]) =
        *reinterpret_cast<const int4*>(&us[r][colu]);
    __syncthreads();
  }
  if (c == NCHUNK - 1) ULAST[(size_t)b * SW + tid] = ul[tid];
}

// ---------------- FUSED MLP (64KB LDS, 2 blocks/CU) --------------------------
// 512 thr (8 waves), M-slab 128. LDS 64KB:
//   phase 1: A dbuf [0,32K) bytes | W1 dbuf [32K,64K)      [unchanged from r7]
//   phase 2: H tile [0,32K) | W2 ping-pong [32K,48K)/[48K,64K) (128x64 tiles)
//   epilogue: scratch [0,32K) per 128-col quarter
// Phase 2: 8 rounds r -> (nh2=r>>1 quarter of N, ks=r&1 half of H-k).
__global__ __launch_bounds__(512, 2) void k_mlp(const __hip_bfloat16* __restrict__ A,
                                                const __hip_bfloat16* __restrict__ W1,
                                                const __hip_bfloat16* __restrict__ W2,
                                                const float* __restrict__ b1,
                                                const float* __restrict__ b2,
                                                __hip_bfloat16* __restrict__ Fout) {
  __shared__ unsigned short smem[32768] __attribute__((aligned(16)));  // 64 KB
  const int tid = threadIdx.x;
  const int lane = tid & 63;
  const int wv = tid >> 6;
  const int hwr = wv >> 1, hwc = wv & 1;   // phase-1 wave grid 4x2 (tile 32x64)
  const int fwr = wv >> 2, fwc = wv & 3;   // phase-2 wave grid 2x4 (tile 64x32/round)
  const size_t m0 = (size_t)blockIdx.x * 128;

  unsigned short* Hs = smem;               // phase-2 H tile at byte 0

  f32x4 Facc[4][4][2];                     // [nh2 quarter][m][n]
#pragma unroll
  for (int q = 0; q < 4; ++q)
#pragma unroll
    for (int m = 0; m < 4; ++m)
#pragma unroll
      for (int n = 0; n < 2; ++n) Facc[q][m][n] = (f32x4)0.f;

  for (int hb = 0; hb < 4; ++hb) {
    f32x4 Hacc[2][4];
#pragma unroll
    for (int m = 0; m < 2; ++m)
#pragma unroll
      for (int n = 0; n < 4; ++n) Hacc[m][n] = (f32x4)0.f;

    // ---- phase 1: H(:, hb*128..+128) accum over K=512 (unchanged) ----
    auto stage1 = [&](int kt, int buf) {
#pragma unroll
      for (int s = 0; s < 2; ++s) {
        int idx = s * 512 + tid;
        int row = idx >> 3, pg = idx & 7;
        int sg = pg ^ (row & 7);
        gload_lds16(A + (m0 + row) * 512 + kt * 64 + sg * 8,
                    (const char*)smem + buf * 16384 + idx * 16);
        gload_lds16(W1 + (size_t)(hb * 128 + row) * 512 + kt * 64 + sg * 8,
                    (const char*)smem + 32768 + buf * 16384 + idx * 16);
      }
    };
    stage1(0, 0);
    __syncthreads();
    for (int kt = 0; kt < 8; ++kt) {
      if (kt < 7) stage1(kt + 1, (kt + 1) & 1);
      const int buf = kt & 1;
      const unsigned short* Ab = smem + buf * 8192;
      const unsigned short* W1b_ = smem + 16384 + buf * 8192;
#pragma unroll
      for (int kh = 0; kh < 2; ++kh) {
        bf16x8 af[2], bfw[4];
#pragma unroll
        for (int m = 0; m < 2; ++m) {
          int row = hwr * 32 + m * 16 + (lane & 15);
          int lg = kh * 4 + (lane >> 4);
          int phys = lg ^ (row & 7);
          af[m] = *reinterpret_cast<const bf16x8*>(&Ab[row * 64 + phys * 8]);
        }
#pragma unroll
        for (int n = 0; n < 4; ++n) {
          int row = hwc * 64 + n * 16 + (lane & 15);
          int lg = kh * 4 + (lane >> 4);
          int phys = lg ^ (row & 7);
          bfw[n] = *reinterpret_cast<const bf16x8*>(&W1b_[row * 64 + phys * 8]);
        }
#pragma unroll
        for (int m = 0; m < 2; ++m)
#pragma unroll
          for (int n = 0; n < 4; ++n)
            Hacc[m][n] = __builtin_amdgcn_mfma_f32_16x16x32_bf16(af[m], bfw[n], Hacc[m][n], 0, 0, 0);
      }
      __syncthreads();
    }

    // issue W2 round-0 tile (nh2=0, ks=0) into region0 = [32K,48K) (dead W1 buf0)
    {
#pragma unroll
      for (int s = 0; s < 2; ++s) {
        int idx = s * 512 + tid;           // 1024 granules (128 rows x 8)
        int row = idx >> 3, pg = idx & 7;
        int sg = pg ^ (row & 7);
        gload_lds16(W2 + (size_t)row * 512 + hb * 128 + sg * 8,
                    (const char*)smem + 32768 + idx * 16);
      }
    }

    // Hacc + b1 -> relu -> Hs at [0,32K) (dead A dbuf), swizzled [128][16g]
    {
      const int rl = (lane >> 4) * 4;
      const int cl = lane & 15;
#pragma unroll
      for (int m = 0; m < 2; ++m)
#pragma unroll
        for (int n = 0; n < 4; ++n) {
          int coll = hwc * 64 + n * 16 + cl;
          float bv = b1[hb * 128 + coll];
#pragma unroll
          for (int r = 0; r < 4; ++r) {
            int rowl = hwr * 32 + m * 16 + rl + r;
            float h = Hacc[m][n][r] + bv;
            h = h > 0.f ? h : 0.f;
            int phys = (coll >> 3) ^ (rowl & 15);
            Hs[rowl * 128 + phys * 8 + (coll & 7)] = bf16bits(h);
          }
        }
    }
    __syncthreads();  // drains W2 r=0 staging + Hs writes

    // ---- phase 2: 8 rounds, Facc[nh2] += H(ks-slice) @ W2-tile^T ----
#pragma unroll
    for (int r = 0; r < 8; ++r) {
      if (r < 7) {
        int rn = r + 1;
        int ksn = rn & 1, nh2n = rn >> 1;
        int regbyte = 32768 + ((rn & 1) ? 16384 : 0);
#pragma unroll
        for (int s = 0; s < 2; ++s) {
          int idx = s * 512 + tid;
          int row = idx >> 3, pg = idx & 7;
          int sg = pg ^ (row & 7);
          gload_lds16(W2 + (size_t)(nh2n * 128 + row) * 512 + hb * 128 + ksn * 64 + sg * 8,
                      (const char*)smem + regbyte + idx * 16);
        }
      }
      const int ks = r & 1, nh2 = r >> 1;
      const unsigned short* w2b = smem + 16384 + ((r & 1) ? 8192 : 0);  // ushort off
#pragma unroll
      for (int kh = 0; kh < 2; ++kh) {
        bf16x8 afH[4], bf2[2];
#pragma unroll
        for (int m = 0; m < 4; ++m) {
          int row = fwr * 64 + m * 16 + (lane & 15);
          int hg = ks * 8 + kh * 4 + (lane >> 4);
          int phys = hg ^ (row & 15);
          afH[m] = *reinterpret_cast<const bf16x8*>(&Hs[row * 128 + phys * 8]);
        }
#pragma unroll
        for (int n = 0; n < 2; ++n) {
          int row = fwc * 32 + n * 16 + (lane & 15);
          int lg = kh * 4 + (lane >> 4);
          int phys = lg ^ (row & 7);
          bf2[n] = *reinterpret_cast<const bf16x8*>(&w2b[row * 64 + phys * 8]);
        }
#pragma unroll
        for (int m = 0; m < 4; ++m)
#pragma unroll
          for (int n = 0; n < 2; ++n)
            Facc[nh2][m][n] = __builtin_amdgcn_mfma_f32_16x16x32_bf16(afH[m], bf2[n], Facc[nh2][m][n], 0, 0, 0);
      }
      __syncthreads();
    }
  }

  // ---- F epilogue: per 128-col quarter, Facc + b2 -> scratch -> int4 stores --
  const int rl = (lane >> 4) * 4;
  const int cl = lane & 15;
#pragma unroll
  for (int q = 0; q < 4; ++q) {
#pragma unroll
    for (int m = 0; m < 4; ++m)
#pragma unroll
      for (int n = 0; n < 2; ++n) {
        int coll = fwc * 32 + n * 16 + cl;            // within 128
        float bv = b2[q * 128 + coll];
#pragma unroll
        for (int r = 0; r < 4; ++r) {
          int rowl = fwr * 64 + m * 16 + rl + r;
          float v = Facc[q][m][n][r] + bv;
          int phys = (coll >> 3) ^ (rowl & 15);
          smem[rowl * 128 + phys * 8 + (coll & 7)] = bf16bits(v);
        }
      }
    __syncthreads();
#pragma unroll
    for (int s = 0; s < 4; ++s) {
      int idx = s * 512 + tid;                        // 2048 granules
      int rowl = idx >> 4, g = idx & 15;
      int phys = g ^ (rowl & 15);
      *reinterpret_cast<int4*>(Fout + (m0 + rowl) * 512 + q * 128 + g * 8) =
          *reinterpret_cast<const int4*>(&smem[rowl * 128 + phys * 8]);
    }
    __syncthreads();
  }
}

// ---------------- stage 3a: 8-deep staged register gather --------------------
__global__ __launch_bounds__(512) void k_s3a(const __hip_bfloat16* __restrict__ F,
                                             const int* __restrict__ IDXI,
                                             float* __restrict__ P3) {
  __shared__ unsigned short fs[8][SW] __attribute__((aligned(16)));
  int c = blockIdx.x, b = blockIdx.y, tid = threadIdx.x;
  const int r = tid >> 6;
  const int colf = (tid & 63) * 8;
  float acc = 0.f;
  int t0 = c * CLEN;
  for (int tt = 0; tt < CLEN; tt += 8) {
    *reinterpret_cast<int4*>(&fs[r][colf]) =
        *reinterpret_cast<const int4*>(&F[((size_t)(t0 + tt + r) * BATCH + b) * SW + colf]);
    __syncthreads();
#pragma unroll
    for (int k = 0; k < 8; ++k) {
      int t = t0 + tt + k;
      if (t < T_STEPS - 1) {
        int i0 = IDXI[(size_t)t * SW + tid];
        acc += bf16val(fs[k][i0]);
      }
    }
    __syncthreads();
  }
  P3[((size_t)c * BATCH + b) * SW + tid] = acc;
}

// ---------------- exact fp32 final step (+ fused s3b) ------------------------
__global__ __launch_bounds__(512) void k_final(const float* __restrict__ P3,
                                               const int* __restrict__ FW,
                                               const float* __restrict__ ULAST,
                                               const float* __restrict__ W1,
                                               const float* __restrict__ b1,
                                               const float* __restrict__ W2,
                                               const float* __restrict__ b2,
                                               float* __restrict__ out) {
  __shared__ float ml[SW] __attribute__((aligned(16)));
  __shared__ float uc[SW] __attribute__((aligned(16)));
  __shared__ float hh[SW] __attribute__((aligned(16)));
  int b = blockIdx.x, j = threadIdx.x;
  float s = 0.f;
  for (int c = 0; c < NCHUNK; ++c) s += P3[((size_t)c * BATCH + b) * SW + j];
  ml[j] = s;
  __syncthreads();
  float e = ml[FW[(size_t)(T_STEPS - 1) * SW + j]];
  float u = ULAST[(size_t)b * SW + j] + EPS * e;
  uc[j] = u;
  __syncthreads();
  float pre = b1[j];
  {
    const f32x4* wr = (const f32x4*)(W1 + (size_t)j * SW);
    const f32x4* uv = (const f32x4*)uc;
    for (int k = 0; k < SW / 4; ++k) {
      f32x4 wv = wr[k], vv = uv[k];
      pre += wv[0] * vv[0] + wv[1] * vv[1] + wv[2] * vv[2] + wv[3] * vv[3];
    }
  }
  hh[j] = pre > 0.f ? pre : 0.f;
  __syncthreads();
  float d = b2[j];
  {
    const f32x4* wr = (const f32x4*)(W2 + (size_t)j * SW);
    const f32x4* hv = (const f32x4*)hh;
    for (int k = 0; k < SW / 4; ++k) {
      f32x4 wv = wr[k], vv = hv[k];
      d += wv[0] * vv[0] + wv[1] * vv[1] + wv[2] * vv[2] + wv[3] * vv[3];
    }
  }
  float sT = u + EPS * d;
  out[BATCH * 128 + (size_t)b * SW + j] = sT;                // last  [64,512]
  if (j >= SW - 128) out[b * 128 + (j - (SW - 128))] = sT;   // outputs [64,128]
}

// ---------------- host -------------------------------------------------------
extern "C" void kernel_launch(void* const* d_in, const int* in_sizes, int n_in,
                              void* d_out, int out_size, void* d_ws, size_t ws_size,
                              hipStream_t stream) {
  const float* x = (const float*)d_in[0];
  const float* init = (const float*)d_in[1];
  const float* W1 = (const float*)d_in[2];
  const float* b1 = (const float*)d_in[3];
  const float* W2 = (const float*)d_in[4];
  const float* b2 = (const float*)d_in[5];
  const int* perm = (const int*)d_in[6];
  float* out = (float*)d_out;

  char* w = (char*)d_ws;
  size_t off = 0;
  auto alloc = [&](size_t bytes) {
    size_t o = off;
    off = (off + bytes + 255) & ~(size_t)255;
    return o;
  };
  size_t oFW   = alloc((size_t)(T_STEPS + 1) * SW * 4);
  size_t oIDXI = alloc((size_t)(T_STEPS + 1) * SW * 4);
  size_t oFWQ  = alloc((size_t)NQ * SW * 4);
  size_t oIDXQ = alloc((size_t)NQ * SW * 4);
  size_t oW1b  = alloc((size_t)SW * SW * 2);
  size_t oW2b  = alloc((size_t)SW * SW * 2);
  size_t oU    = alloc((size_t)T_STEPS * BATCH * SW * 2);  // aliased as F
  size_t oP1   = alloc((size_t)NCHUNK * BATCH * SW * 4);
  size_t oP3   = alloc((size_t)NCHUNK * BATCH * SW * 4);
  size_t oUL   = alloc((size_t)BATCH * SW * 4);
  if (off > ws_size) return;

  int* FW = (int*)(w + oFW);
  int* IDXI = (int*)(w + oIDXI);
  int* FWQ = (int*)(w + oFWQ);
  int* IDXIQ = (int*)(w + oIDXQ);
  __hip_bfloat16* W1b = (__hip_bfloat16*)(w + oW1b);
  __hip_bfloat16* W2b = (__hip_bfloat16*)(w + oW2b);
  __hip_bfloat16* U = (__hip_bfloat16*)(w + oU);
  float* P1 = (float*)(w + oP1);
  float* P3 = (float*)(w + oP3);
  float* ULAST = (float*)(w + oUL);

  k_tabA<<<1, 512, 0, stream>>>(perm, FW, IDXI);
  k_tabB<<<1, 512, 0, stream>>>(FW, IDXI, FWQ, IDXIQ);
  k_tabC<<<T_STEPS + 1, 512, 0, stream>>>(FWQ, IDXIQ, FW, IDXI);
  k_wcast<<<(2 * SW * SW + 255) / 256, 256, 0, stream>>>(W1, W2, W1b, W2b);

  k_s1a<<<dim3(NCHUNK, BATCH), 512, 0, stream>>>(x, IDXI, P1);
  k_s1b<<<BATCH, 512, 0, stream>>>(init, P1);
  k_s1c<<<dim3(NCHUNK, BATCH), 512, 0, stream>>>(x, IDXI, P1, U, ULAST);

  k_mlp<<<(T_STEPS * BATCH) / 128, 512, 0, stream>>>(U, W1b, W2b, b1, b2, U);

  k_s3a<<<dim3(NCHUNK, BATCH), 512, 0, stream>>>(U, IDXI, P3);

  k_final<<<BATCH, 512, 0, stream>>>(P3, FW, ULAST, W1, b1, W2, b2, out);
}

// Round 11
// 520.104 us; speedup vs baseline: 1.1616x; 1.1616x over previous
//
#include <hip/hip_runtime.h>
#include <hip/hip_bf16.h>
#include <stdint.h>

// ResRnn via first-order expansion in eps (method err ~1e-3 << 2.62):
//   tables: pi^t / pi^-t via composition doubling
//   stage1: permuted prefix sum -> U (bf16) + ULAST (fp32)  [8-deep reg-gather]
//   k_mlp : FUSED F = relu(U@W1^T+b1)@W2^T + b2
//           [r9 structure + depth-3 counted-vmcnt pipeline in phase 1]
//   stage3: e-reduction as register gather with inverse table [8-deep]
//   final : exact fp32 last step (+ fused s3b column-sum/gather).

#define T_STEPS 2048
#define BATCH 64
#define IN_W 256
#define SW 512
#define EPS 1e-5f
#define NCHUNK 64
#define CLEN 32
#define QSTEP 32
#define NQ 65

typedef __bf16 bf16x8 __attribute__((ext_vector_type(8)));
typedef float f32x4 __attribute__((ext_vector_type(4)));

__device__ __forceinline__ unsigned short bf16bits(float v) {
  __hip_bfloat16 h = __float2bfloat16(v);
  return *reinterpret_cast<unsigned short*>(&h);
}

__device__ __forceinline__ float bf16val(unsigned short u) {
  unsigned int x = ((unsigned int)u) << 16;
  return __uint_as_float(x);
}

__device__ __forceinline__ void gload_lds16(const void* g, const void* l) {
  __builtin_amdgcn_global_load_lds(
      (const __attribute__((address_space(1))) unsigned int*)(uintptr_t)g,
      (__attribute__((address_space(3))) unsigned int*)(uintptr_t)l, 16, 0, 0);
}

// ---------------- permutation power tables (doubling) ------------------------
__global__ __launch_bounds__(512) void k_tabA(const int* __restrict__ perm,
                                              int* __restrict__ FW, int* __restrict__ IDXI) {
  __shared__ int pl[SW], il[SW];
  int j = threadIdx.x;
  pl[j] = perm[j];
  __syncthreads();
  il[pl[j]] = j;
  __syncthreads();
  int f = j, iv = j;
  FW[j] = f; IDXI[j] = iv;
  for (int t = 1; t <= QSTEP; ++t) {
    f = pl[f]; iv = il[iv];
    FW[t * SW + j] = f; IDXI[t * SW + j] = iv;
  }
}

__global__ __launch_bounds__(512) void k_tabB(const int* __restrict__ FW, const int* __restrict__ IDXI,
                                              int* __restrict__ FWQ, int* __restrict__ IDXIQ) {
  __shared__ int f32r[SW], i32r[SW];
  int j = threadIdx.x;
  f32r[j] = FW[QSTEP * SW + j];
  i32r[j] = IDXI[QSTEP * SW + j];
  __syncthreads();
  int f = j, iv = j;
  FWQ[j] = f; IDXIQ[j] = iv;
  for (int q = 1; q < NQ; ++q) {
    f = f32r[f]; iv = i32r[iv];
    FWQ[q * SW + j] = f; IDXIQ[q * SW + j] = iv;
  }
}

__global__ __launch_bounds__(512) void k_tabC(const int* __restrict__ FWQ, const int* __restrict__ IDXIQ,
                                              int* __restrict__ FW, int* __restrict__ IDXI) {
  int t = blockIdx.x;
  if (t <= QSTEP) return;
  int j = threadIdx.x;
  int q = t >> 5, r = t & 31;
  int a = FW[r * SW + j];
  FW[(size_t)t * SW + j] = FWQ[q * SW + a];
  int b = IDXI[r * SW + j];
  IDXI[(size_t)t * SW + j] = IDXIQ[q * SW + b];
}

// ---------------- weights -> bf16 --------------------------------------------
__global__ __launch_bounds__(256) void k_wcast(const float* __restrict__ W1,
                                               const float* __restrict__ W2,
                                               __hip_bfloat16* __restrict__ W1b,
                                               __hip_bfloat16* __restrict__ W2b) {
  int i = blockIdx.x * 256 + threadIdx.x;
  if (i < SW * SW) W1b[i] = __float2bfloat16(W1[i]);
  else W2b[i - SW * SW] = __float2bfloat16(W2[i - SW * SW]);
}

// ---------------- stage 1a: chunk sums, 8-deep staged register gather --------
__global__ __launch_bounds__(512) void k_s1a(const float* __restrict__ x,
                                             const int* __restrict__ IDXI,
                                             float* __restrict__ P1) {
  __shared__ float xs[8][IN_W] __attribute__((aligned(16)));
  int c = blockIdx.x, b = blockIdx.y, tid = threadIdx.x;
  const int r = tid >> 6;
  const int colx = (tid & 63) * 4;
  float acc = 0.f;
  int t0 = c * CLEN;
  for (int tt = 0; tt < CLEN; tt += 8) {
    *reinterpret_cast<f32x4*>(&xs[r][colx]) =
        *reinterpret_cast<const f32x4*>(&x[((size_t)(t0 + tt + r) * BATCH + b) * IN_W + colx]);
    __syncthreads();
#pragma unroll
    for (int k = 0; k < 8; ++k) {
      int i0 = IDXI[(size_t)(t0 + tt + k) * SW + tid];
      if (i0 < IN_W) acc += xs[k][i0];
    }
    __syncthreads();
  }
  P1[((size_t)c * BATCH + b) * SW + tid] = acc;
}

__global__ __launch_bounds__(512) void k_s1b(const float* __restrict__ init,
                                             float* __restrict__ P1) {
  int b = blockIdx.x, i = threadIdx.x;
  float run = EPS * init[i];
  for (int c = 0; c < NCHUNK; ++c) {
    size_t o = ((size_t)c * BATCH + b) * SW + i;
    float t = P1[o]; P1[o] = run; run += t;
  }
}

// ---------------- stage 1c: prefix walk, 8-deep staging, coalesced U dump ----
__global__ __launch_bounds__(512) void k_s1c(const float* __restrict__ x,
                                             const int* __restrict__ IDXI,
                                             const float* __restrict__ P1,
                                             __hip_bfloat16* __restrict__ U,
                                             float* __restrict__ ULAST) {
  __shared__ float xs[8][IN_W] __attribute__((aligned(16)));
  __shared__ unsigned short us[8][SW] __attribute__((aligned(16)));
  __shared__ float ul[SW] __attribute__((aligned(16)));
  int c = blockIdx.x, b = blockIdx.y, tid = threadIdx.x;
  float v = P1[((size_t)c * BATCH + b) * SW + tid];
  int t0 = c * CLEN;
  const int r = tid >> 6;
  const int colx = (tid & 63) * 4;
  const int colu = (tid & 63) * 8;
  for (int tt = 0; tt < CLEN; tt += 8) {
    *reinterpret_cast<f32x4*>(&xs[r][colx]) =
        *reinterpret_cast<const f32x4*>(&x[((size_t)(t0 + tt + r) * BATCH + b) * IN_W + colx]);
    __syncthreads();
#pragma unroll
    for (int k = 0; k < 8; ++k) {
      int t = t0 + tt + k;
      int i0 = IDXI[(size_t)t * SW + tid];
      int i1 = IDXI[(size_t)(t + 1) * SW + tid];
      if (i0 < IN_W) v += xs[k][i0];
      us[k][i1] = bf16bits(v);
      if (t == T_STEPS - 1) ul[i1] = v;
    }
    __syncthreads();
    *reinterpret_cast<int4*>(&U[((size_t)(t0 + tt + r) * BATCH + b) * SW + colu]) =
        *reinterpret_cast<const int4*>(&us[r][colu]);
    __syncthreads();
  }
  if (c == NCHUNK - 1) ULAST[(size_t)b * SW + tid] = ul[tid];
}

// ---------------- FUSED MLP: r9 structure + depth-3 phase-1 pipeline ---------
// 512 thr (8 waves), M-slab 128. LDS 128KB (bytes):
//   phase 1: A bufs x3  [0,48K)      | W1 bufs x3 [48K,96K)
//   phase 2: W2 ping-pong [0,32K)/[32K,64K) | Hs [96K,128K)
//   epilogue: scratch [0,64K)
// Phase 1: counted vmcnt(4) + raw s_barrier; tile kt+2 issued after barrier.
__global__ __launch_bounds__(512, 2) void k_mlp(const __hip_bfloat16* __restrict__ A,
                                                const __hip_bfloat16* __restrict__ W1,
                                                const __hip_bfloat16* __restrict__ W2,
                                                const float* __restrict__ b1,
                                                const float* __restrict__ b2,
                                                __hip_bfloat16* __restrict__ Fout) {
  __shared__ unsigned short smem[65536] __attribute__((aligned(16)));  // 128 KB
  const int tid = threadIdx.x;
  const int lane = tid & 63;
  const int wv = tid >> 6;
  const int hwr = wv >> 1, hwc = wv & 1;   // phase-1 wave grid 4x2 (tile 32x64)
  const int fwr = wv >> 2, fwc = wv & 3;   // phase-2 wave grid 2x4 (tile 64x128)
  const size_t m0 = (size_t)blockIdx.x * 128;

  unsigned short* Hs = smem + 49152;       // byte 98304, 32KB

  f32x4 Facc[2][4][4];
#pragma unroll
  for (int nh = 0; nh < 2; ++nh)
#pragma unroll
    for (int m = 0; m < 4; ++m)
#pragma unroll
      for (int n = 0; n < 4; ++n) Facc[nh][m][n] = (f32x4)0.f;

  for (int hb = 0; hb < 4; ++hb) {
    f32x4 Hacc[2][4];
#pragma unroll
    for (int m = 0; m < 2; ++m)
#pragma unroll
      for (int n = 0; n < 4; ++n) Hacc[m][n] = (f32x4)0.f;

    // ---- phase 1: H(:, hb*128..+128) accum over K=512, depth-3 pipeline ----
    auto stage1 = [&](int kt, int buf) {
#pragma unroll
      for (int s = 0; s < 2; ++s) {
        int idx = s * 512 + tid;           // 1024 granules: row*8+pg
        int row = idx >> 3, pg = idx & 7;
        int sg = pg ^ (row & 7);
        gload_lds16(A + (m0 + row) * 512 + kt * 64 + sg * 8,
                    (const char*)smem + buf * 16384 + idx * 16);
        gload_lds16(W1 + (size_t)(hb * 128 + row) * 512 + kt * 64 + sg * 8,
                    (const char*)smem + 98304 / 2 + buf * 16384 + idx * 16);  // byte 49152
      }
    };
    stage1(0, 0);
    stage1(1, 1);
#pragma unroll
    for (int kt = 0; kt < 8; ++kt) {
      // wait: tile kt landed (kt+1 / kt+2 may stay in flight), then rendezvous
      if (kt < 7) asm volatile("s_waitcnt vmcnt(4)" ::: "memory");
      else        asm volatile("s_waitcnt vmcnt(0)" ::: "memory");
      __builtin_amdgcn_s_barrier();
      if (kt < 6) stage1(kt + 2, (kt + 2) % 3);  // writes buf (kt-1)%3: readers done
      const int buf = kt % 3;
      const unsigned short* Ab = smem + buf * 8192;
      const unsigned short* W1b_ = smem + 24576 + buf * 8192;
#pragma unroll
      for (int kh = 0; kh < 2; ++kh) {
        bf16x8 af[2], bfw[4];
#pragma unroll
        for (int m = 0; m < 2; ++m) {
          int row = hwr * 32 + m * 16 + (lane & 15);
          int lg = kh * 4 + (lane >> 4);
          int phys = lg ^ (row & 7);
          af[m] = *reinterpret_cast<const bf16x8*>(&Ab[row * 64 + phys * 8]);
        }
#pragma unroll
        for (int n = 0; n < 4; ++n) {
          int row = hwc * 64 + n * 16 + (lane & 15);
          int lg = kh * 4 + (lane >> 4);
          int phys = lg ^ (row & 7);
          bfw[n] = *reinterpret_cast<const bf16x8*>(&W1b_[row * 64 + phys * 8]);
        }
#pragma unroll
        for (int m = 0; m < 2; ++m)
#pragma unroll
          for (int n = 0; n < 4; ++n)
            Hacc[m][n] = __builtin_amdgcn_mfma_f32_16x16x32_bf16(af[m], bfw[n], Hacc[m][n], 0, 0, 0);
      }
    }
    __syncthreads();  // full drain: all phase-1 LDS reads done before reuse

    // issue W2 round-0 tile (256x64) into region0 [0,32K) (dead A bufs 0,1)
    {
#pragma unroll
      for (int s = 0; s < 4; ++s) {
        int idx = s * 512 + tid;           // 2048 granules (256 rows x 8)
        int row = idx >> 3, pg = idx & 7;
        int sg = pg ^ (row & 7);
        gload_lds16(W2 + (size_t)row * 512 + hb * 128 + sg * 8,
                    (const char*)smem + idx * 16);
      }
    }

    // Hacc + b1 -> relu -> Hs [96K,128K), swizzled [128][16 granules]
    {
      const int rl = (lane >> 4) * 4;
      const int cl = lane & 15;
#pragma unroll
      for (int m = 0; m < 2; ++m)
#pragma unroll
        for (int n = 0; n < 4; ++n) {
          int coll = hwc * 64 + n * 16 + cl;
          float bv = b1[hb * 128 + coll];
#pragma unroll
          for (int r = 0; r < 4; ++r) {
            int rowl = hwr * 32 + m * 16 + rl + r;
            float h = Hacc[m][n][r] + bv;
            h = h > 0.f ? h : 0.f;
            int phys = (coll >> 3) ^ (rowl & 15);
            Hs[rowl * 128 + phys * 8 + (coll & 7)] = bf16bits(h);
          }
        }
    }
    __syncthreads();  // drains W2 r=0 staging + Hs writes

    // ---- phase 2: 4 rounds (r9 logic), Facc[nh] += H(ks) @ W2-tile^T ----
#pragma unroll
    for (int r = 0; r < 4; ++r) {
      if (r < 3) {
        int rn = r + 1;
        int ksn = rn >> 1, nhn = rn & 1;
        int regbyte = (rn & 1) ? 32768 : 0;
#pragma unroll
        for (int s = 0; s < 4; ++s) {
          int idx = s * 512 + tid;
          int row = idx >> 3, pg = idx & 7;
          int sg = pg ^ (row & 7);
          gload_lds16(W2 + (size_t)(nhn * 256 + row) * 512 + hb * 128 + ksn * 64 + sg * 8,
                      (const char*)smem + regbyte + idx * 16);
        }
      }
      const int ks = r >> 1, nh = r & 1;
      const unsigned short* w2b = smem + ((r & 1) ? 16384 : 0);  // ushort offset
#pragma unroll
      for (int kh = 0; kh < 2; ++kh) {
        bf16x8 afH[4], bf2[4];
#pragma unroll
        for (int m = 0; m < 4; ++m) {
          int row = fwr * 64 + m * 16 + (lane & 15);
          int hg = ks * 8 + kh * 4 + (lane >> 4);
          int phys = hg ^ (row & 15);
          afH[m] = *reinterpret_cast<const bf16x8*>(&Hs[row * 128 + phys * 8]);
        }
#pragma unroll
        for (int n = 0; n < 4; ++n) {
          int row = fwc * 64 + n * 16 + (lane & 15);
          int lg = kh * 4 + (lane >> 4);
          int phys = lg ^ (row & 7);
          bf2[n] = *reinterpret_cast<const bf16x8*>(&w2b[row * 64 + phys * 8]);
        }
#pragma unroll
        for (int m = 0; m < 4; ++m)
#pragma unroll
          for (int n = 0; n < 4; ++n)
            Facc[nh][m][n] = __builtin_amdgcn_mfma_f32_16x16x32_bf16(afH[m], bf2[n], Facc[nh][m][n], 0, 0, 0);
      }
      __syncthreads();
    }
  }

  // ---- F epilogue: Facc + b2 -> scratch LDS [128][256] -> coalesced int4 ----
  const int rl = (lane >> 4) * 4;
  const int cl = lane & 15;
#pragma unroll
  for (int nh = 0; nh < 2; ++nh) {
#pragma unroll
    for (int m = 0; m < 4; ++m)
#pragma unroll
      for (int n = 0; n < 4; ++n) {
        int coll = fwc * 64 + n * 16 + cl;            // within 256
        float bv = b2[nh * 256 + coll];
#pragma unroll
        for (int r = 0; r < 4; ++r) {
          int rowl = fwr * 64 + m * 16 + rl + r;
          float v = Facc[nh][m][n][r] + bv;
          int phys = (coll >> 3) ^ (rowl & 31);
          smem[rowl * 256 + phys * 8 + (coll & 7)] = bf16bits(v);
        }
      }
    __syncthreads();
#pragma unroll
    for (int s = 0; s < 8; ++s) {
      int idx = s * 512 + tid;                        // 4096 granules
      int rowl = idx >> 5, g = idx & 31;
      int phys = g ^ (rowl & 31);
      *reinterpret_cast<int4*>(Fout + (m0 + rowl) * 512 + nh * 256 + g * 8) =
          *reinterpret_cast<const int4*>(&smem[rowl * 256 + phys * 8]);
    }
    __syncthreads();
  }
}

// ---------------- stage 3a: 8-deep staged register gather --------------------
__global__ __launch_bounds__(512) void k_s3a(const __hip_bfloat16* __restrict__ F,
                                             const int* __restrict__ IDXI,
                                             float* __restrict__ P3) {
  __shared__ unsigned short fs[8][SW] __attribute__((aligned(16)));
  int c = blockIdx.x, b = blockIdx.y, tid = threadIdx.x;
  const int r = tid >> 6;
  const int colf = (tid & 63) * 8;
  float acc = 0.f;
  int t0 = c * CLEN;
  for (int tt = 0; tt < CLEN; tt += 8) {
    *reinterpret_cast<int4*>(&fs[r][colf]) =
        *reinterpret_cast<const int4*>(&F[((size_t)(t0 + tt + r) * BATCH + b) * SW + colf]);
    __syncthreads();
#pragma unroll
    for (int k = 0; k < 8; ++k) {
      int t = t0 + tt + k;
      if (t < T_STEPS - 1) {
        int i0 = IDXI[(size_t)t * SW + tid];
        acc += bf16val(fs[k][i0]);
      }
    }
    __syncthreads();
  }
  P3[((size_t)c * BATCH + b) * SW + tid] = acc;
}

// ---------------- exact fp32 final step (+ fused s3b) ------------------------
__global__ __launch_bounds__(512) void k_final(const float* __restrict__ P3,
                                               const int* __restrict__ FW,
                                               const float* __restrict__ ULAST,
                                               const float* __restrict__ W1,
                                               const float* __restrict__ b1,
                                               const float* __restrict__ W2,
                                               const float* __restrict__ b2,
                                               float* __restrict__ out) {
  __shared__ float ml[SW] __attribute__((aligned(16)));
  __shared__ float uc[SW] __attribute__((aligned(16)));
  __shared__ float hh[SW] __attribute__((aligned(16)));
  int b = blockIdx.x, j = threadIdx.x;
  float s = 0.f;
  for (int c = 0; c < NCHUNK; ++c) s += P3[((size_t)c * BATCH + b) * SW + j];
  ml[j] = s;
  __syncthreads();
  float e = ml[FW[(size_t)(T_STEPS - 1) * SW + j]];
  float u = ULAST[(size_t)b * SW + j] + EPS * e;
  uc[j] = u;
  __syncthreads();
  float pre = b1[j];
  {
    const f32x4* wr = (const f32x4*)(W1 + (size_t)j * SW);
    const f32x4* uv = (const f32x4*)uc;
    for (int k = 0; k < SW / 4; ++k) {
      f32x4 wv = wr[k], vv = uv[k];
      pre += wv[0] * vv[0] + wv[1] * vv[1] + wv[2] * vv[2] + wv[3] * vv[3];
    }
  }
  hh[j] = pre > 0.f ? pre : 0.f;
  __syncthreads();
  float d = b2[j];
  {
    const f32x4* wr = (const f32x4*)(W2 + (size_t)j * SW);
    const f32x4* hv = (const f32x4*)hh;
    for (int k = 0; k < SW / 4; ++k) {
      f32x4 wv = wr[k], vv = hv[k];
      d += wv[0] * vv[0] + wv[1] * vv[1] + wv[2] * vv[2] + wv[3] * vv[3];
    }
  }
  float sT = u + EPS * d;
  out[BATCH * 128 + (size_t)b * SW + j] = sT;                // last  [64,512]
  if (j >= SW - 128) out[b * 128 + (j - (SW - 128))] = sT;   // outputs [64,128]
}

// ---------------- host -------------------------------------------------------
extern "C" void kernel_launch(void* const* d_in, const int* in_sizes, int n_in,
                              void* d_out, int out_size, void* d_ws, size_t ws_size,
                              hipStream_t stream) {
  const float* x = (const float*)d_in[0];
  const float* init = (const float*)d_in[1];
  const float* W1 = (const float*)d_in[2];
  const float* b1 = (const float*)d_in[3];
  const float* W2 = (const float*)d_in[4];
  const float* b2 = (const float*)d_in[5];
  const int* perm = (const int*)d_in[6];
  float* out = (float*)d_out;

  char* w = (char*)d_ws;
  size_t off = 0;
  auto alloc = [&](size_t bytes) {
    size_t o = off;
    off = (off + bytes + 255) & ~(size_t)255;
    return o;
  };
  size_t oFW   = alloc((size_t)(T_STEPS + 1) * SW * 4);
  size_t oIDXI = alloc((size_t)(T_STEPS + 1) * SW * 4);
  size_t oFWQ  = alloc((size_t)NQ * SW * 4);
  size_t oIDXQ = alloc((size_t)NQ * SW * 4);
  size_t oW1b  = alloc((size_t)SW * SW * 2);
  size_t oW2b  = alloc((size_t)SW * SW * 2);
  size_t oU    = alloc((size_t)T_STEPS * BATCH * SW * 2);  // aliased as F
  size_t oP1   = alloc((size_t)NCHUNK * BATCH * SW * 4);
  size_t oP3   = alloc((size_t)NCHUNK * BATCH * SW * 4);
  size_t oUL   = alloc((size_t)BATCH * SW * 4);
  if (off > ws_size) return;

  int* FW = (int*)(w + oFW);
  int* IDXI = (int*)(w + oIDXI);
  int* FWQ = (int*)(w + oFWQ);
  int* IDXIQ = (int*)(w + oIDXQ);
  __hip_bfloat16* W1b = (__hip_bfloat16*)(w + oW1b);
  __hip_bfloat16* W2b = (__hip_bfloat16*)(w + oW2b);
  __hip_bfloat16* U = (__hip_bfloat16*)(w + oU);
  float* P1 = (float*)(w + oP1);
  float* P3 = (float*)(w + oP3);
  float* ULAST = (float*)(w + oUL);

  k_tabA<<<1, 512, 0, stream>>>(perm, FW, IDXI);
  k_tabB<<<1, 512, 0, stream>>>(FW, IDXI, FWQ, IDXIQ);
  k_tabC<<<T_STEPS + 1, 512, 0, stream>>>(FWQ, IDXIQ, FW, IDXI);
  k_wcast<<<(2 * SW * SW + 255) / 256, 256, 0, stream>>>(W1, W2, W1b, W2b);

  k_s1a<<<dim3(NCHUNK, BATCH), 512, 0, stream>>>(x, IDXI, P1);
  k_s1b<<<BATCH, 512, 0, stream>>>(init, P1);
  k_s1c<<<dim3(NCHUNK, BATCH), 512, 0, stream>>>(x, IDXI, P1, U, ULAST);

  k_mlp<<<(T_STEPS * BATCH) / 128, 512, 0, stream>>>(U, W1b, W2b, b1, b2, U);

  k_s3a<<<dim3(NCHUNK, BATCH), 512, 0, stream>>>(U, IDXI, P3);

  k_final<<<BATCH, 512, 0, stream>>>(P3, FW, ULAST, W1, b1, W2, b2, out);
}